// Round 4
// baseline (47.385 us; speedup 1.0000x reference)
//
#include <hip/hip_runtime.h>
#include <math.h>

#define PP 9       // K*K
#define NK 5       // k's per half (half0: k=0..4, half1: k=5..8 + dummy)
#define CAPS 32
#define PS 16
#define OH 15
#define HH 32
#define WW 32
#define LN_2PI 1.8378770664093453f

typedef float f32x2 __attribute__((ext_vector_type(2)));

__device__ __forceinline__ float frcp(float x) {
    float r;
    asm("v_rcp_f32 %0, %1" : "=v"(r) : "v"(x));
    return r;
}
__device__ __forceinline__ f32x2 splat2(float x) {
    f32x2 r; r.x = x; r.y = x; return r;
}
__device__ __forceinline__ f32x2 pkfma(f32x2 a, f32x2 b, f32x2 c) {
    return __builtin_elementwise_fma(a, b, c);  // -> v_pk_fma_f32 (gfx950 packed fp32)
}

// DPP helpers (VALU pipe): quad_perm xor1=0xB1, xor2=0x4E; row_ror:4=0x124, row_ror:8=0x128.
template <int CTRL>
__device__ __forceinline__ float dppf(float x) {
    int r = __builtin_amdgcn_update_dpp(0, __builtin_bit_cast(int, x), CTRL, 0xF, 0xF, true);
    return __builtin_bit_cast(float, r);
}
__device__ __forceinline__ float row_sum16(float x) {
    x += dppf<0xB1>(x);
    x += dppf<0x4E>(x);
    x += dppf<0x124>(x);
    x += dppf<0x128>(x);
    return x;
}
__device__ __forceinline__ float row_max16(float x) {
    x = fmaxf(x, dppf<0xB1>(x));
    x = fmaxf(x, dppf<0x4E>(x));
    x = fmaxf(x, dppf<0x124>(x));
    x = fmaxf(x, dppf<0x128>(x));
    return x;
}
// xor16 within each 32-lane group (and-mask 0x1F) -> halves stay independent.
__device__ __forceinline__ float swz_xor16(float x) {
    return __builtin_bit_cast(float,
        __builtin_amdgcn_ds_swizzle(__builtin_bit_cast(int, x), 0x401F));
}
// exchange with lane^32 (spans the full 64-lane wave)
__device__ __forceinline__ float xhalf(float x) {
    return __shfl_xor(x, 32);
}
__device__ __forceinline__ f32x2 xhalf2(f32x2 x) {
    f32x2 r; r.x = __shfl_xor(x.x, 32); r.y = __shfl_xor(x.y, 32); return r;
}

// SPLIT-K layout: one wave = ONE site; lane = half*32 + c. Each thread owns
// capsule c, ALL 16 pose elems, and 5 of the 9 kernel positions (half0 k=0..4,
// half1 k=5..8 + a zeroed dummy). Why this beats both prior layouts:
//  - vs R0/R3 (2 sites/wave): v state halves (v[5][8] f32x2 = 80 regs) ->
//    fits __launch_bounds__(64,3) (170-reg cap) with NO AGPR backing store,
//    killing ~650 v_accvgpr moves/site and lifting occupancy 2->3 waves/SIMD.
//  - vs R1 (split-PS): the per-k softmax chain is NOT duplicated (each half
//    runs chains only for its own k's: 5/site vs R1's 9/site), and the E-step
//    ln-p sum is thread-local (all pose elems in-thread) -> no xhalf there.
// Cross-half traffic only in the M-step: r_sum(1) + mu(16) + sigma(16)
// shuffles per iteration. Both halves hold identical full mu/sigma/r_sum/aoc
// afterward (commutative adds -> bitwise agreement); half 0 stores outputs.
__global__ __launch_bounds__(64, 3) void emcaps_kernel(
    const float* __restrict__ x,      // (32,32,32,32,16)
    const float* __restrict__ a,      // (32,32,32,32)
    const float* __restrict__ wgt,    // (9,32,4,4)
    const float* __restrict__ beta_u, // (32)
    const float* __restrict__ beta_a, // (32)
    float* __restrict__ out_mu,       // (32,15,15,32,16)
    float* __restrict__ out_a)        // (32,15,15,32)
{
    const int lane = threadIdx.x;   // 0..63
    const int half = lane >> 5;     // which k-group
    const int c = lane & 31;        // capsule

    const int site = blockIdx.x;
    const int j = site % OH;
    const int t2 = site / OH;
    const int i = t2 % OH;
    const int b = t2 / OH;
    const int h0 = 2 * i, w0 = 2 * j;

    const float kmask = half ? 0.f : 1.f;   // kills the dummy slot (half1 kk=4)

    // ---- phase 1: global loads (5 pixels/thread; dummy slot zeroed) ----
    f32x2 v[NK][8];    // holds x now; overwritten with votes in phase 2
    float r[NK];
    #pragma unroll
    for (int kk = 0; kk < NK; ++kk) {
        const int kg = half * NK + kk;      // 0..9 (9 = dummy)
        if (kg < PP) {
            const int hh = h0 + kg / 3, ww = w0 + kg % 3;
            const size_t pix = (size_t)(b * HH + hh) * WW + ww;
            const float* xb = x + pix * (CAPS * PS) + c * PS;
            *(float4*)&v[kk][0] = *(const float4*)xb;
            *(float4*)&v[kk][2] = *(const float4*)(xb + 4);
            *(float4*)&v[kk][4] = *(const float4*)(xb + 8);
            *(float4*)&v[kk][6] = *(const float4*)(xb + 12);
            r[kk] = a[pix * CAPS + c] * (1.f / 32.f);  // initial r (it0)
        } else {
            #pragma unroll
            for (int m = 0; m < 8; ++m) v[kk][m] = splat2(0.f);
            r[kk] = 0.f;
        }
    }

    // ---- phase 2: votes in place (weights are L1-hot: 18 KB total) ----
    // pair m covers t=(2m,2m+1): x row base 4*(m>>1)+q; weight pair w2[q*2+(m&1)].
    #pragma unroll
    for (int kk = 0; kk < NK; ++kk) {
        const int kg = half * NK + kk;
        if (kg < PP) {
            float xt[PS];
            #pragma unroll
            for (int m = 0; m < 8; ++m) { xt[2 * m] = v[kk][m].x; xt[2 * m + 1] = v[kk][m].y; }
            f32x2 w2[8];
            const float* wb = wgt + kg * (CAPS * PS) + c * PS;
            *(float4*)&w2[0] = *(const float4*)wb;
            *(float4*)&w2[2] = *(const float4*)(wb + 4);
            *(float4*)&w2[4] = *(const float4*)(wb + 8);
            *(float4*)&w2[6] = *(const float4*)(wb + 12);
            #pragma unroll
            for (int m = 0; m < 8; ++m) {
                f32x2 acc = splat2(0.f);
                #pragma unroll
                for (int q = 0; q < 4; ++q)
                    acc = pkfma(splat2(xt[4 * (m >> 1) + q]), w2[q * 2 + (m & 1)], acc);
                v[kk][m] = acc;
            }
        }
    }

    const float bu = beta_u[c];
    const float ba = beta_a[c];
    const float eps = 1e-6f;
    const float lam = 1e-3f;

    f32x2 mu2[8], is22[8];   // full-site values on BOTH halves (post-exchange)
    float aoc = 0.f;
    float slgfull = 0.f;
    float r_sum;

    for (int it = 0; it < 3; ++it) {
        if (it > 0) {
            // ---- E-step (thread-local ln-p sum; softmax within 32-lane half) ----
            const float addc = __logf(aoc) - slgfull - 8.f * LN_2PI;
            #pragma unroll
            for (int kk = 0; kk < NK; ++kk) {
                f32x2 s2 = splat2(0.f);
                #pragma unroll
                for (int m = 0; m < 8; ++m) {
                    f32x2 d = v[kk][m] - mu2[m];
                    s2 = pkfma(d * d, is22[m], s2);
                }
                const float lnk = addc - (s2.x + s2.y);
                float mx = row_max16(lnk);
                mx = fmaxf(mx, swz_xor16(mx));
                float e = __expf(lnk - mx);
                float ss = row_sum16(e);
                ss += swz_xor16(ss);
                r[kk] = e * frcp(ss);
            }
            r[NK - 1] *= kmask;   // dummy slot back to zero
        }

        // ---- M-step: two-pass (numerically required) ----
        float rp = 0.f;
        #pragma unroll
        for (int kk = 0; kk < NK; ++kk) rp += r[kk];
        r_sum = rp + xhalf(rp);               // full sum over all 9 k
        const float invr = frcp(r_sum + eps);
        f32x2 rr[NK];
        #pragma unroll
        for (int kk = 0; kk < NK; ++kk) { r[kk] *= invr; rr[kk] = splat2(r[kk]); }

        #pragma unroll
        for (int m = 0; m < 8; ++m) {
            f32x2 acc = splat2(0.f);
            #pragma unroll
            for (int kk = 0; kk < NK; ++kk) acc = pkfma(rr[kk], v[kk][m], acc);
            mu2[m] = acc + xhalf2(acc);       // full mu on both halves
        }
        float slg = 0.f;
        #pragma unroll
        for (int m = 0; m < 8; ++m) {
            f32x2 acc = splat2(0.f);
            #pragma unroll
            for (int kk = 0; kk < NK; ++kk) {
                f32x2 d = v[kk][m] - mu2[m];
                acc = pkfma(rr[kk] * d, d, acc);
            }
            f32x2 sg = (acc + xhalf2(acc)) + splat2(eps);   // full sigma
            is22[m].x = frcp(2.f * sg.x);
            is22[m].y = frcp(2.f * sg.y);
            slg += 0.5f * __logf(sg.x * sg.y);   // = 0.5*(log sx + log sy)
        }
        slgfull = slg;                        // already a full 16-elem sum
        const float ch = r_sum * (16.f * bu + slgfull);
        aoc = frcp(1.f + __expf(-lam * (ba - ch)));
    }

    // ---- outputs: half 0 stores the site's mu (64B/thread) + a ----
    if (half == 0) {
        float* ob = out_mu + (size_t)site * (CAPS * PS) + c * PS;
        *(float4*)(ob + 0)  = *(float4*)&mu2[0];
        *(float4*)(ob + 4)  = *(float4*)&mu2[2];
        *(float4*)(ob + 8)  = *(float4*)&mu2[4];
        *(float4*)(ob + 12) = *(float4*)&mu2[6];
        out_a[(size_t)site * CAPS + c] = aoc;
    }
}

extern "C" void kernel_launch(void* const* d_in, const int* in_sizes, int n_in,
                              void* d_out, int out_size, void* d_ws, size_t ws_size,
                              hipStream_t stream) {
    const float* x      = (const float*)d_in[0];
    const float* a      = (const float*)d_in[1];
    const float* wgt    = (const float*)d_in[2];
    const float* beta_u = (const float*)d_in[3];
    const float* beta_a = (const float*)d_in[4];

    float* out_mu = (float*)d_out;
    float* out_a  = (float*)d_out + (size_t)32 * OH * OH * CAPS * PS;  // 3,686,400

    const int n_sites = 32 * OH * OH;  // 7200
    emcaps_kernel<<<n_sites, 64, 0, stream>>>(x, a, wgt, beta_u, beta_a, out_mu, out_a);
}

// Round 7
// 38.129 us; speedup vs baseline: 1.2428x; 1.2428x over previous
//
#include <hip/hip_runtime.h>
#include <math.h>

#define PP 9       // K*K
#define CAPS 32
#define PS 16
#define OH 15
#define HH 32
#define WW 32
#define LN_2PI 1.8378770664093453f

typedef float f32x2 __attribute__((ext_vector_type(2)));

__device__ __forceinline__ float frcp(float x) {
    float r;
    asm("v_rcp_f32 %0, %1" : "=v"(r) : "v"(x));
    return r;
}
__device__ __forceinline__ f32x2 splat2(float x) {
    f32x2 r; r.x = x; r.y = x; return r;
}
__device__ __forceinline__ f32x2 pkfma(f32x2 a, f32x2 b, f32x2 c) {
    return __builtin_elementwise_fma(a, b, c);  // -> v_pk_fma_f32 (gfx950 packed fp32)
}

// DPP helpers (VALU pipe): quad_perm xor1=0xB1, xor2=0x4E; row_ror:4=0x124, row_ror:8=0x128.
template <int CTRL>
__device__ __forceinline__ float dppf(float x) {
    int r = __builtin_amdgcn_update_dpp(0, __builtin_bit_cast(int, x), CTRL, 0xF, 0xF, true);
    return __builtin_bit_cast(float, r);
}
__device__ __forceinline__ float row_sum16(float x) {
    x += dppf<0xB1>(x);
    x += dppf<0x4E>(x);
    x += dppf<0x124>(x);
    x += dppf<0x128>(x);
    return x;
}
__device__ __forceinline__ float row_max16(float x) {
    x = fmaxf(x, dppf<0xB1>(x));
    x = fmaxf(x, dppf<0x4E>(x));
    x = fmaxf(x, dppf<0x124>(x));
    x = fmaxf(x, dppf<0x128>(x));
    return x;
}
// xor16 within each 32-lane group (and-mask 0x1F) -> halves (= the 2 sites)
// stay independent. PROVEN primitive (R3, 38.2us). permlane16_swap was tried
// twice (R5 asm, R6 builtin) and both times the allocator coalesced the two
// identical inputs into ONE register -> in-place row rotation -> 2*x[lane^16]
// instead of x + x[lane^16]. Do not retry with identical inputs.
__device__ __forceinline__ float swz_xor16(float x) {
    return __builtin_bit_cast(float,
        __builtin_amdgcn_ds_swizzle(__builtin_bit_cast(int, x), 0x401F));
}

// R3 layout (best bench: 38.2 us): one 64-lane wave = TWO sites (32 lanes each),
// lane = s*32 + c; each thread owns all 16 pose elems of capsule c of site s.
// All pose math packed f32x2 (v_pk_fma_f32). 16 logf -> 8 logf(sx*sy) / M-step.
//
// NEW vs R3: the E-step is PHASE-BATCHED. R3 wrote the 9 softmax chains as one
// loop; at ~220 live regs of the 256-reg (64,2) budget the scheduler ran the
// chains back-to-back, exposing ~350 serial cycles each (fma chain -> DPP
// reduce -> ds_swizzle round trip -> exp -> DPP -> ds_swizzle -> rcp).
// Batching by PHASE (all 9 lnk, then all 9 row-maxes, then all 9 swizzles
// back-to-back, ...) lets the 9 independent chains' latencies overlap while
// keeping per-chain arithmetic bitwise identical to R3.
__global__ __launch_bounds__(64, 2) void emcaps_kernel(
    const float* __restrict__ x,      // (32,32,32,32,16)
    const float* __restrict__ a,      // (32,32,32,32)
    const float* __restrict__ wgt,    // (9,32,4,4)
    const float* __restrict__ beta_u, // (32)
    const float* __restrict__ beta_a, // (32)
    float* __restrict__ out_mu,       // (32,15,15,32,16)
    float* __restrict__ out_a)        // (32,15,15,32)
{
    const int lane = threadIdx.x;   // 0..63
    const int s = lane >> 5;        // site within pair
    const int c = lane & 31;        // capsule

    const int site = blockIdx.x * 2 + s;
    const int j = site % OH;
    const int t2 = site / OH;
    const int i = t2 % OH;
    const int b = t2 / OH;
    const int h0 = 2 * i, w0 = 2 * j;

    // ---- phase 1: all global loads issued back-to-back ----
    f32x2 v[PP][8];    // holds x now; overwritten with votes in phase 2
    float r[PP];
    #pragma unroll
    for (int k = 0; k < PP; ++k) {
        const int hh = h0 + k / 3, ww = w0 + k % 3;
        const size_t pix = (size_t)(b * HH + hh) * WW + ww;
        const float* xb = x + pix * (CAPS * PS) + c * PS;
        *(float4*)&v[k][0] = *(const float4*)xb;
        *(float4*)&v[k][2] = *(const float4*)(xb + 4);
        *(float4*)&v[k][4] = *(const float4*)(xb + 8);
        *(float4*)&v[k][6] = *(const float4*)(xb + 12);
        r[k] = a[pix * CAPS + c] * (1.f / 32.f);  // initial r (it0)
    }

    // ---- phase 2: votes in place (weights are L1-hot: 18 KB total) ----
    // pair m covers t=(2m,2m+1): x row idx 4*(m>>1)+q; weight pair w2[q*2+(m&1)].
    #pragma unroll
    for (int k = 0; k < PP; ++k) {
        float xt[PS];
        #pragma unroll
        for (int m = 0; m < 8; ++m) { xt[2 * m] = v[k][m].x; xt[2 * m + 1] = v[k][m].y; }
        f32x2 w2[8];
        const float* wb = wgt + k * (CAPS * PS) + c * PS;
        *(float4*)&w2[0] = *(const float4*)wb;
        *(float4*)&w2[2] = *(const float4*)(wb + 4);
        *(float4*)&w2[4] = *(const float4*)(wb + 8);
        *(float4*)&w2[6] = *(const float4*)(wb + 12);
        #pragma unroll
        for (int m = 0; m < 8; ++m) {
            f32x2 acc = splat2(0.f);
            #pragma unroll
            for (int q = 0; q < 4; ++q)
                acc = pkfma(splat2(xt[4 * (m >> 1) + q]), w2[q * 2 + (m & 1)], acc);
            v[k][m] = acc;
        }
    }

    const float bu = beta_u[c];
    const float ba = beta_a[c];
    const float eps = 1e-6f;
    const float lam = 1e-3f;

    f32x2 mu2[8], is22[8];   // is22 = 1/(2*sigma^2)
    float aoc = 0.f;
    float slgfull = 0.f;
    float r_sum;

    for (int it = 0; it < 3; ++it) {
        if (it > 0) {
            // ---- E-step: phase-batched across the 9 independent k-chains ----
            const float addc = __logf(aoc) - slgfull - 8.f * LN_2PI;
            float lnk[PP], red[PP];
            #pragma unroll
            for (int k = 0; k < PP; ++k) {          // phase A: ln-posteriors
                f32x2 s2 = splat2(0.f);
                #pragma unroll
                for (int m = 0; m < 8; ++m) {
                    f32x2 d = v[k][m] - mu2[m];
                    s2 = pkfma(d * d, is22[m], s2);
                }
                lnk[k] = addc - (s2.x + s2.y);
            }
            #pragma unroll
            for (int k = 0; k < PP; ++k) red[k] = row_max16(lnk[k]);   // B: DPP maxes
            #pragma unroll
            for (int k = 0; k < PP; ++k)                                // C: 9 swizzles
                red[k] = fmaxf(red[k], swz_xor16(red[k]));              //    pipelined
            #pragma unroll
            for (int k = 0; k < PP; ++k) lnk[k] = __expf(lnk[k] - red[k]); // D: exps
            #pragma unroll
            for (int k = 0; k < PP; ++k) red[k] = row_sum16(lnk[k]);   // E: DPP sums
            #pragma unroll
            for (int k = 0; k < PP; ++k)                                // F: 9 swizzles
                red[k] += swz_xor16(red[k]);                            //    pipelined
            #pragma unroll
            for (int k = 0; k < PP; ++k) r[k] = lnk[k] * frcp(red[k]); // G: normalize
        }

        // ---- M-step: two-pass (numerically required) ----
        r_sum = 0.f;
        #pragma unroll
        for (int k = 0; k < PP; ++k) r_sum += r[k];
        const float invr = frcp(r_sum + eps);
        f32x2 rr[PP];
        #pragma unroll
        for (int k = 0; k < PP; ++k) { r[k] *= invr; rr[k] = splat2(r[k]); }

        #pragma unroll
        for (int m = 0; m < 8; ++m) {
            f32x2 acc = splat2(0.f);
            #pragma unroll
            for (int k = 0; k < PP; ++k) acc = pkfma(rr[k], v[k][m], acc);
            mu2[m] = acc;
        }
        float slg = 0.f;
        #pragma unroll
        for (int m = 0; m < 8; ++m) {
            f32x2 acc = splat2(0.f);
            #pragma unroll
            for (int k = 0; k < PP; ++k) {
                f32x2 d = v[k][m] - mu2[m];
                acc = pkfma(rr[k] * d, d, acc);
            }
            f32x2 sg = acc + splat2(eps);
            is22[m].x = frcp(2.f * sg.x);
            is22[m].y = frcp(2.f * sg.y);
            slg += 0.5f * __logf(sg.x * sg.y);   // = 0.5*(log sx + log sy)
        }
        slgfull = slg;
        const float ch = r_sum * (16.f * bu + slgfull);
        aoc = frcp(1.f + __expf(-lam * (ba - ch)));
    }

    // ---- outputs: each thread stores its 16 mu's (64B) + its a ----
    float* ob = out_mu + (size_t)site * (CAPS * PS) + c * PS;
    *(float4*)(ob + 0)  = *(float4*)&mu2[0];
    *(float4*)(ob + 4)  = *(float4*)&mu2[2];
    *(float4*)(ob + 8)  = *(float4*)&mu2[4];
    *(float4*)(ob + 12) = *(float4*)&mu2[6];
    out_a[(size_t)site * CAPS + c] = aoc;
}

extern "C" void kernel_launch(void* const* d_in, const int* in_sizes, int n_in,
                              void* d_out, int out_size, void* d_ws, size_t ws_size,
                              hipStream_t stream) {
    const float* x      = (const float*)d_in[0];
    const float* a      = (const float*)d_in[1];
    const float* wgt    = (const float*)d_in[2];
    const float* beta_u = (const float*)d_in[3];
    const float* beta_a = (const float*)d_in[4];

    float* out_mu = (float*)d_out;
    float* out_a  = (float*)d_out + (size_t)32 * OH * OH * CAPS * PS;  // 3,686,400

    const int n_sites = 32 * OH * OH;  // 7200
    emcaps_kernel<<<n_sites / 2, 64, 0, stream>>>(x, a, wgt, beta_u, beta_a, out_mu, out_a);
}